// Round 2
// baseline (363.468 us; speedup 1.0000x reference)
//
#include <hip/hip_runtime.h>

typedef __attribute__((ext_vector_type(8))) short short8;
typedef __attribute__((ext_vector_type(4))) float f32x4;
typedef __attribute__((ext_vector_type(4))) unsigned short u16x4;

#define GLOAD16(g, l)                                                          \
  __builtin_amdgcn_global_load_lds(                                            \
      (const __attribute__((address_space(1))) unsigned int*)(g),              \
      (__attribute__((address_space(3))) unsigned int*)(l), 16, 0, 0)

__device__ __forceinline__ unsigned short f2bf(float f) {
  unsigned int u = __float_as_uint(f);
  u += 0x7FFFu + ((u >> 16) & 1u);   // RNE
  return (unsigned short)(u >> 16);
}
__device__ __forceinline__ float bf2f(unsigned short h) {
  return __uint_as_float(((unsigned int)h) << 16);
}

// ---------------------------------------------------------------- mix / bmix
__global__ void mix_kernel(const float* __restrict__ amp,
                           const float* __restrict__ phase,
                           const float* __restrict__ bias,
                           float* __restrict__ mix, float* __restrict__ bmix) {
  int q = blockIdx.x * blockDim.x + threadIdx.x;  // 0..1023
  float a[16];
  float mx = -1e30f;
  for (int s = 0; s < 16; ++s) {
    a[s] = amp[s * 1024 + q];
    mx = fmaxf(mx, a[s]);
  }
  float sum = 0.f;
  for (int s = 0; s < 16; ++s) {
    a[s] = __expf(a[s] - mx);
    sum += a[s];
  }
  float inv = 1.f / sum;
  for (int s = 0; s < 16; ++s) {
    float m = a[s] * inv * cosf(phase[s * 1024 + q]);
    mix[s * 1024 + q] = m;
    bmix[s * 1024 + q] = bias[s * 1024 + q] * m;
  }
}

// ---------------------------------------------------------------- cast x->bf16
__global__ void cast_x_kernel(const float* __restrict__ x,
                              unsigned short* __restrict__ xb) {
  int i = (blockIdx.x * blockDim.x + threadIdx.x) * 4;
  float4 v = *(const float4*)(x + i);
  union { unsigned short h[4]; uint2 u; } o;
  o.h[0] = f2bf(v.x); o.h[1] = f2bf(v.y); o.h[2] = f2bf(v.z); o.h[3] = f2bf(v.w);
  *(uint2*)(xb + i) = o.u;
}

// ------------------------------------------------- transpose+cast W -> Wt bf16
// W[s][i][q] f32 -> Wt[s][q][i] bf16. Coalesced 256B reads along q; each lane
// packs 8 i-values into one short8 store (L2 accumulates full lines).
__global__ void transpose_w_kernel(const float* __restrict__ W,
                                   unsigned short* __restrict__ Wt) {
  const int s = blockIdx.y;
  const int q = blockIdx.x * 64 + (threadIdx.x & 63);
  const int w = threadIdx.x >> 6;  // wave 0..3 -> i-range w*256..+255
  const float* Ws = W + (size_t)s * 1048576;
  unsigned short* Wts = Wt + (size_t)s * 1048576 + (size_t)q * 1024;
  for (int i0 = w * 256; i0 < w * 256 + 256; i0 += 8) {
    union { unsigned short h[8]; short8 v; } o;
    #pragma unroll
    for (int k = 0; k < 8; ++k)
      o.h[k] = f2bf(Ws[(size_t)(i0 + k) * 1024 + q]);
    *(short8*)(Wts + i0) = o.v;
  }
}

// ---------------------------------------------------------------- bf16 GEMM
// C[m][n] = sum_k xb[m][k]*Wt[n][k]; 256x256 tile, BK=32, 8 waves (2Mx4N),
// 3-buffer LDS, counted vmcnt(4), raw s_barrier, setprio around MFMA cluster.
template <bool BF16SUP>
__global__ __launch_bounds__(512, 2) void gemm_kernel(
    const unsigned short* __restrict__ xb, const unsigned short* __restrict__ wt,
    const float* __restrict__ mix, const float* __restrict__ bmix,
    float* __restrict__ outf, unsigned short* __restrict__ sup) {
  __shared__ __align__(16) unsigned short As[3][256 * 32];
  __shared__ __align__(16) unsigned short Bs[3][256 * 32];

  const int tid = threadIdx.x;
  const int lane = tid & 63;
  const int wv = tid >> 6;
  const int wm = wv >> 2, wn = wv & 3;   // 2 x 4 waves, wave tile 128x64
  const int lr = lane & 15;
  const int lk = (lane >> 4) * 8;

  // XCD-aware swizzle (1024 % 8 == 0 -> simple form is bijective)
  const int id = blockIdx.x;
  const int swz = (id & 7) * 128 + (id >> 3);
  const int by = swz >> 6, bx = swz & 63;
  const int m0 = by * 256, n0 = bx * 256;

  const int srow = tid >> 2, scol = (tid & 3) * 8;
  const unsigned short* gA = xb + (size_t)(m0 + srow) * 1024 + scol;
  const unsigned short* gB = wt + (size_t)(n0 + srow) * 1024 + scol;
  const int ldst = tid * 8;  // element offset, round 0

#define STAGE(kt, b) do {                                                      \
    const unsigned short* _a = gA + (kt) * 32;                                 \
    const unsigned short* _b = gB + (kt) * 32;                                 \
    GLOAD16(_a, &As[b][ldst]);                                                 \
    GLOAD16(_a + 128 * 1024, &As[b][4096 + ldst]);                             \
    GLOAD16(_b, &Bs[b][ldst]);                                                 \
    GLOAD16(_b + 128 * 1024, &Bs[b][4096 + ldst]);                             \
  } while (0)

  f32x4 acc[8][4];
  #pragma unroll
  for (int i = 0; i < 8; ++i)
    #pragma unroll
    for (int j = 0; j < 4; ++j) acc[i][j] = (f32x4){0.f, 0.f, 0.f, 0.f};

  // prologue: stage tiles 0,1; wait tile 0 (4 loads may remain in flight)
  STAGE(0, 0);
  STAGE(1, 1);
  asm volatile("s_waitcnt vmcnt(4)" ::: "memory");
  __builtin_amdgcn_s_barrier();

  int cb = 0;
  for (int kt = 0; kt < 32; ++kt) {
    if (kt < 30) {
      int nb = cb + 2; if (nb >= 3) nb -= 3;   // == (kt+2)%3, last read at kt-1
      STAGE(kt + 2, nb);
    }
    short8 af[8], bv[4];
    const unsigned short* Ab = &As[cb][(wm * 128 + lr) * 32 + lk];
    #pragma unroll
    for (int mi = 0; mi < 8; ++mi)
      af[mi] = *(const short8*)(Ab + mi * 16 * 32);
    const unsigned short* Bb = &Bs[cb][(wn * 64 + lr) * 32 + lk];
    #pragma unroll
    for (int ni = 0; ni < 4; ++ni)
      bv[ni] = *(const short8*)(Bb + ni * 16 * 32);
    __builtin_amdgcn_s_setprio(1);
    #pragma unroll
    for (int mi = 0; mi < 8; ++mi)
      #pragma unroll
      for (int ni = 0; ni < 4; ++ni)
        acc[mi][ni] = __builtin_amdgcn_mfma_f32_16x16x32_bf16(
            af[mi], bv[ni], acc[mi][ni], 0, 0, 0);
    __builtin_amdgcn_s_setprio(0);
    if (kt < 30) {
      asm volatile("s_waitcnt vmcnt(4)" ::: "memory");  // tile kt+1 landed
    } else {
      asm volatile("s_waitcnt vmcnt(0)" ::: "memory");  // tail drain
    }
    __builtin_amdgcn_sched_barrier(0);
    __builtin_amdgcn_s_barrier();
    cb += 1; if (cb >= 3) cb -= 3;
  }
#undef STAGE

  // epilogue: sup = acc*mix + bmix
  #pragma unroll
  for (int ni = 0; ni < 4; ++ni) {
    const int n = n0 + wn * 64 + ni * 16 + lr;
    const float mv = mix[n];
    const float bvv = bmix[n];
    #pragma unroll
    for (int mi = 0; mi < 8; ++mi) {
      const int m = m0 + wm * 128 + mi * 16 + (lane >> 4) * 4;
      #pragma unroll
      for (int r = 0; r < 4; ++r) {
        float v = acc[mi][ni][r] * mv + bvv;
        if (BF16SUP)
          sup[(size_t)(m + r) * 16384 + n] = f2bf(v);
        else
          outf[(size_t)(m + r) * 16384 + n] = v;
      }
    }
  }
}

// ------------------------------------------------------- LN from bf16 sup
__global__ __launch_bounds__(256) void ln_bf16_kernel(
    const unsigned short* __restrict__ sup, float* __restrict__ out,
    const float* __restrict__ gamma, const float* __restrict__ beta) {
  __shared__ float red[8];
  const int t = threadIdx.x;
  const size_t base = (size_t)blockIdx.x * 1024;
  u16x4 raw = *(const u16x4*)(sup + base + t * 4);
  float v[4];
  #pragma unroll
  for (int j = 0; j < 4; ++j) v[j] = bf2f(raw[j]);
  float s = v[0] + v[1] + v[2] + v[3];
  float ss = v[0] * v[0] + v[1] * v[1] + v[2] * v[2] + v[3] * v[3];
  #pragma unroll
  for (int m = 32; m >= 1; m >>= 1) {
    s += __shfl_xor(s, m);
    ss += __shfl_xor(ss, m);
  }
  const int wv = t >> 6;
  if ((t & 63) == 0) { red[wv * 2] = s; red[wv * 2 + 1] = ss; }
  __syncthreads();
  const float S = red[0] + red[2] + red[4] + red[6];
  const float SS = red[1] + red[3] + red[5] + red[7];
  const float mean = S * (1.0f / 1024.0f);
  const float var = SS * (1.0f / 1024.0f) - mean * mean;
  const float rstd = rsqrtf(var + 1e-5f);
  const float4 g = *(const float4*)(gamma + t * 4);
  const float4 b = *(const float4*)(beta + t * 4);
  float4 o;
  o.x = (v[0] - mean) * rstd * g.x + b.x;
  o.y = (v[1] - mean) * rstd * g.y + b.y;
  o.z = (v[2] - mean) * rstd * g.z + b.z;
  o.w = (v[3] - mean) * rstd * g.w + b.w;
  *(float4*)(out + base + t * 4) = o;
}

// ------------------------------------------------------- in-place f32 LN (fallback)
__global__ __launch_bounds__(256) void ln_kernel(float* __restrict__ out,
                                                 const float* __restrict__ gamma,
                                                 const float* __restrict__ beta) {
  __shared__ float red[8];
  const int t = threadIdx.x;
  const size_t base = (size_t)blockIdx.x * 1024;
  float4 v = *(const float4*)(out + base + t * 4);
  float s = v.x + v.y + v.z + v.w;
  float ss = v.x * v.x + v.y * v.y + v.z * v.z + v.w * v.w;
  #pragma unroll
  for (int m = 32; m >= 1; m >>= 1) {
    s += __shfl_xor(s, m);
    ss += __shfl_xor(ss, m);
  }
  const int wv = t >> 6;
  if ((t & 63) == 0) { red[wv * 2] = s; red[wv * 2 + 1] = ss; }
  __syncthreads();
  const float S = red[0] + red[2] + red[4] + red[6];
  const float SS = red[1] + red[3] + red[5] + red[7];
  const float mean = S * (1.0f / 1024.0f);
  const float var = SS * (1.0f / 1024.0f) - mean * mean;
  const float rstd = rsqrtf(var + 1e-5f);
  const float4 g = *(const float4*)(gamma + t * 4);
  const float4 b = *(const float4*)(beta + t * 4);
  float4 o;
  o.x = (v.x - mean) * rstd * g.x + b.x;
  o.y = (v.y - mean) * rstd * g.y + b.y;
  o.z = (v.z - mean) * rstd * g.z + b.z;
  o.w = (v.w - mean) * rstd * g.w + b.w;
  *(float4*)(out + base + t * 4) = o;
}

extern "C" void kernel_launch(void* const* d_in, const int* in_sizes, int n_in,
                              void* d_out, int out_size, void* d_ws, size_t ws_size,
                              hipStream_t stream) {
  (void)in_sizes; (void)n_in; (void)out_size;
  const float* x     = (const float*)d_in[0];  // [4096,1024]
  const float* W     = (const float*)d_in[1];  // [16,1024,1024]
  const float* bias  = (const float*)d_in[2];  // [16,1024]
  const float* amp   = (const float*)d_in[3];  // [16,1024]
  const float* phase = (const float*)d_in[4];  // [16,1024]
  const float* gamma = (const float*)d_in[5];  // [1024]
  const float* beta  = (const float*)d_in[6];  // [1024]
  float* out = (float*)d_out;                  // [4096,16,1024]

  char* ws = (char*)d_ws;
  unsigned short* Wt   = (unsigned short*)ws;                        // 32 MiB
  unsigned short* xbuf = (unsigned short*)(ws + 33554432);           //  8 MiB
  float* mixp  = (float*)(ws + 33554432 + 8388608);                  // 64 KiB
  float* bmixp = mixp + 16384;                                       // 64 KiB
  unsigned short* sup  = (unsigned short*)(ws + 33554432 + 8388608 + 131072); // 128 MiB

  const bool big = ws_size >= (size_t)176291840ULL;

  hipLaunchKernelGGL(mix_kernel, dim3(4), dim3(256), 0, stream, amp, phase, bias, mixp, bmixp);
  hipLaunchKernelGGL(cast_x_kernel, dim3(4096), dim3(256), 0, stream, x, xbuf);
  hipLaunchKernelGGL(transpose_w_kernel, dim3(16, 16), dim3(256), 0, stream, W, Wt);
  if (big) {
    hipLaunchKernelGGL((gemm_kernel<true>), dim3(1024), dim3(512), 0, stream,
                       xbuf, Wt, mixp, bmixp, out, sup);
    hipLaunchKernelGGL(ln_bf16_kernel, dim3(65536), dim3(256), 0, stream, sup, out, gamma, beta);
  } else {
    hipLaunchKernelGGL((gemm_kernel<false>), dim3(1024), dim3(512), 0, stream,
                       xbuf, Wt, mixp, bmixp, out, sup);
    hipLaunchKernelGGL(ln_kernel, dim3(65536), dim3(256), 0, stream, out, gamma, beta);
  }
}